// Round 7
// baseline (159.185 us; speedup 1.0000x reference)
//
#include <hip/hip_runtime.h>
#include <hip/hip_bf16.h>

#define EMBED 768
#define NHEADS 8
#define HDIM 96
#define SEQ 2048
#define BATCH 4
#define NTOK (BATCH*SEQ)   // 8192
#define QKVN (3*EMBED)     // 2304

// 1/sqrt(96) * log2(e): softmax computed in exp2 domain
#define QSCALE 0.14724444f

typedef __attribute__((ext_vector_type(4))) float f32x4;
typedef __attribute__((ext_vector_type(8))) __bf16 bf16x8;

__device__ __forceinline__ unsigned short f2bf(float f) {
  union { float f; unsigned int u; } c; c.f = f;
  unsigned int u = c.u;
  return (unsigned short)((u + 0x7FFFu + ((u >> 16) & 1u)) >> 16);
}

// v_cvt_pk_bf16_f32: packs (lo,hi) -> dword of 2 bf16 (gfx950)
__device__ __forceinline__ unsigned int cvt_pk_bf16(float lo, float hi) {
  unsigned int r;
  asm("v_cvt_pk_bf16_f32 %0, %1, %2" : "=v"(r) : "v"(lo), "v"(hi));
  return r;
}

__device__ __forceinline__ void gload_lds16(const void* g, void* l) {
  __builtin_amdgcn_global_load_lds(
      (const __attribute__((address_space(1))) unsigned int*)g,
      (__attribute__((address_space(3))) unsigned int*)l, 16, 0, 0);
}

// ---------------- cast x -> bf16 ----------------
__global__ __launch_bounds__(256) void cast_x_kernel(const float4* __restrict__ in,
                                                     ushort4* __restrict__ out, int n4) {
  int i = blockIdx.x * 256 + threadIdx.x;
  if (i >= n4) return;
  float4 v = in[i];
  out[i] = make_ushort4(f2bf(v.x), f2bf(v.y), f2bf(v.z), f2bf(v.w));
}

// ---------------- transpose+cast W [R][C] f32 -> [C'][R] bf16 ----------------
// remap=1 (W_qkv): out row = (c%3)*768 + c/3  (de-interleave qkv -> [which][h][d])
__global__ __launch_bounds__(256) void transpose_cast_kernel(const float* __restrict__ in,
                                                             unsigned short* __restrict__ out,
                                                             int R, int C, int remap) {
  __shared__ float t[32][33];
  int c0 = blockIdx.x * 32, r0 = blockIdx.y * 32;
  int tx = threadIdx.x & 31, ty = threadIdx.x >> 5;  // 32 x 8
  #pragma unroll
  for (int i = 0; i < 32; i += 8)
    t[ty + i][tx] = in[(size_t)(r0 + ty + i) * C + c0 + tx];
  __syncthreads();
  #pragma unroll
  for (int i = 0; i < 32; i += 8) {
    int c = c0 + ty + i;
    int rp = remap ? (c % 3) * 768 + c / 3 : c;
    out[(size_t)rp * R + r0 + tx] = f2bf(t[tx][ty + i]);
  }
}

// ---------------- GEMM, T2+T3/T4+T5 stack (unchanged from round 6) ----------------
template <int MODE>
__global__ __launch_bounds__(256, 2) void gemm8_kernel(
    const unsigned short* __restrict__ A, const unsigned short* __restrict__ B,
    const float* __restrict__ bias, int K, int NB,
    unsigned short* __restrict__ Qo, unsigned short* __restrict__ Ko,
    unsigned short* __restrict__ Vt, float* __restrict__ out) {
  __shared__ unsigned short As[2][128 * 64];  // 32 KB (row stride 128 B, swizzled)
  __shared__ unsigned short Bs[2][128 * 64];  // 32 KB
  const int tid = threadIdx.x;
  const int lane = tid & 63, wid = tid >> 6;
  const int wr = wid >> 1, wc = wid & 1;
  const int l15 = lane & 15, l16 = lane >> 4;
  const int cpx = gridDim.x >> 3;
  const int bid = blockIdx.x;
  const int swz = (bid & 7) * cpx + (bid >> 3);
  const int my = swz / NB, nx = swz - my * NB;
  const int m0 = my * 128, n0 = nx * 128;

  auto stage_half = [&](int buf, int kt, int half) {
    const unsigned short* src = half ? B : A;
    const int base0 = half ? n0 : m0;
    char* dst = (char*)(half ? &Bs[buf][0] : &As[buf][0]);
    #pragma unroll
    for (int i = 0; i < 4; i++) {
      int c = i * 256 + tid;
      int r = c >> 3, s = c & 7;
      gload_lds16(src + (size_t)(base0 + r) * K + kt * 64 + ((s ^ (r & 7)) << 3),
                  dst + (i * 256 + wid * 64) * 16);
    }
  };

  f32x4 acc[4][4] = {};
  const int xr = (l15 & 7) << 4;

  stage_half(0, 0, 0);
  stage_half(0, 0, 1);
  asm volatile("s_waitcnt vmcnt(0)" ::: "memory");
  __builtin_amdgcn_s_barrier();

  const int NT = K >> 6;
  for (int t = 0; t < NT; ++t) {
    const int cur = t & 1;
    const char* Ac = (const char*)&As[cur][0];
    const char* Bc = (const char*)&Bs[cur][0];
    #pragma unroll
    for (int kh = 0; kh < 2; ++kh) {
      bf16x8 af[4], bfr[4];
      #pragma unroll
      for (int mi = 0; mi < 4; mi++)
        af[mi] = *(const bf16x8*)(Ac + (wr * 64 + mi * 16 + l15) * 128 +
                                  ((kh * 64 + l16 * 16) ^ xr));
      #pragma unroll
      for (int ni = 0; ni < 4; ni++)
        bfr[ni] = *(const bf16x8*)(Bc + (wc * 64 + ni * 16 + l15) * 128 +
                                   ((kh * 64 + l16 * 16) ^ xr));
      if (t + 1 < NT) stage_half(cur ^ 1, t + 1, kh);
      __builtin_amdgcn_s_barrier();
      __builtin_amdgcn_s_setprio(1);
      #pragma unroll
      for (int mi = 0; mi < 4; mi++)
        #pragma unroll
        for (int ni = 0; ni < 4; ni++)
          acc[mi][ni] = __builtin_amdgcn_mfma_f32_16x16x32_bf16(af[mi], bfr[ni], acc[mi][ni], 0, 0, 0);
      __builtin_amdgcn_s_setprio(0);
      __builtin_amdgcn_s_barrier();
    }
    asm volatile("s_waitcnt lgkmcnt(0)" ::: "memory");
    asm volatile("s_waitcnt vmcnt(0)" ::: "memory");
    __builtin_amdgcn_sched_barrier(0);
    __builtin_amdgcn_s_barrier();
  }

  if (MODE == 0) {
    #pragma unroll
    for (int mi = 0; mi < 4; mi++) {
      #pragma unroll
      for (int ni = 0; ni < 4; ni++) {
        int base = n0 + wc * 64 + ni * 16;
        int which = base / 768;
        int hd = base - which * 768;
        int h = hd / 96;
        int d0 = hd - h * 96;
        float bb = bias[(hd + l15) * 3 + which];
        int rowb = m0 + wr * 64 + mi * 16 + l16 * 4;
        int bi = rowb >> 11, nnb = rowb & 2047;
        size_t bh = (size_t)(bi * NHEADS + h);
        if (which == 2) {
          int nn2 = (nnb & ~63) | (nnb & 32) | ((nnb & 12) << 1) | ((nnb & 16) >> 2) | (nnb & 3);
          float v0 = acc[mi][ni][0] + bb, v1 = acc[mi][ni][1] + bb;
          float v2 = acc[mi][ni][2] + bb, v3 = acc[mi][ni][3] + bb;
          uint2 pk;
          pk.x = cvt_pk_bf16(v0, v1);
          pk.y = cvt_pk_bf16(v2, v3);
          *(uint2*)(Vt + (bh * HDIM + d0 + l15) * SEQ + nn2) = pk;
        } else {
          #pragma unroll
          for (int j = 0; j < 4; j++) {
            float v = acc[mi][ni][j] + bb;
            int nn = nnb + j;
            if (which == 0) Qo[(bh * SEQ + nn) * HDIM + d0 + l15] = f2bf(v * QSCALE);
            else            Ko[(bh * SEQ + nn) * HDIM + d0 + l15] = f2bf(v);
          }
        }
      }
    }
  } else {
    #pragma unroll
    for (int mi = 0; mi < 4; mi++) {
      #pragma unroll
      for (int ni = 0; ni < 4; ni++) {
        int col = n0 + wc * 64 + ni * 16 + l15;
        float bb = bias[col];
        #pragma unroll
        for (int j = 0; j < 4; j++) {
          int row = m0 + wr * 64 + mi * 16 + l16 * 4 + j;
          out[(size_t)row * EMBED + col] = acc[mi][ni][j] + bb;
        }
      }
    }
  }
}

// ---------------- flash attention v3: 8 waves x 16 q-rows, register P ----------------
// Q [B*H][N][96] bf16 (pre-scaled), K same, Vt [B*H][96][N] bf16 (pi-permuted cols).
// Out: attn [B][N][H*96] bf16. KVBLK=64 double-buffered, 1 barrier/iter.
// 512 threads, LDS 48 KB -> 2 blocks/CU = 16 waves/CU = 4 waves/SIMD.
__global__ __launch_bounds__(512) void attn_kernel(
    const unsigned short* __restrict__ Q, const unsigned short* __restrict__ Kd,
    const unsigned short* __restrict__ Vt, unsigned short* __restrict__ Oa) {
  __shared__ unsigned short Ks[2][64 * 96];   // row-major [64][96]
  __shared__ unsigned short Vs[2][96 * 64];   // [d][sigma-k], 16B slots XOR (d&7)

  const int tid = threadIdx.x, lane = tid & 63, wid = tid >> 6;  // wid 0..7
  const int l15 = lane & 15, l16 = lane >> 4;
  const int bid = blockIdx.x;
  const int swz = (bid & 7) * 64 + (bid >> 3);
  const int qb_ = swz & 15, bh = swz >> 4;
  const int bi = bh >> 3, h = bh & 7;
  const int q0 = qb_ * 128;

  const unsigned short* Qg = Q + ((size_t)bh * SEQ + q0) * HDIM;
  const unsigned short* Kg = Kd + (size_t)bh * SEQ * HDIM;
  const unsigned short* Vg = Vt + (size_t)bh * HDIM * SEQ;

  // this wave's 16 q-rows as MFMA B-fragments (col = q = l15)
  bf16x8 qf[3];
  #pragma unroll
  for (int ks = 0; ks < 3; ks++)
    qf[ks] = *(const bf16x8*)(Qg + (size_t)(wid * 16 + l15) * HDIM + ks * 32 + l16 * 8);

  // staging with 512 threads: 768 16B-chunks each for K and V
  auto stageKV = [&](int buf, int k0) {
    gload_lds16(Kg + (size_t)k0 * HDIM + tid * 8, (char*)&Ks[buf][0] + wid * 1024);
    if (wid < 4)
      gload_lds16(Kg + (size_t)k0 * HDIM + (512 + tid) * 8,
                  (char*)&Ks[buf][0] + 8192 + wid * 1024);
    {
      int d = tid >> 3, s = tid & 7;
      gload_lds16(Vg + (size_t)d * SEQ + k0 + ((s ^ (d & 7)) << 3),
                  (char*)&Vs[buf][0] + wid * 1024);
    }
    if (wid < 4) {
      int idx = 512 + tid, d = idx >> 3, s = idx & 7;
      gload_lds16(Vg + (size_t)d * SEQ + k0 + ((s ^ (d & 7)) << 3),
                  (char*)&Vs[buf][0] + 8192 + wid * 1024);
    }
  };

  f32x4 oacc[6] = {};            // O^T: lane d = d6*16+l16*4+j, q = l15
  float mrow = -__builtin_inff(), lrow = 0.f;

  stageKV(0, 0);
  __syncthreads();

  for (int kb = 0; kb < SEQ / 64; kb++) {
    const int cur = kb & 1;
    if (kb + 1 < SEQ / 64) stageKV(cur ^ 1, (kb + 1) * 64);

    const char* Kc = (const char*)&Ks[cur][0];
    const char* Vc = (const char*)&Vs[cur][0];

    // ---- S^T = K Q^T : lane holds kv = 16*ni+4*l16+j, q = l15 ----
    f32x4 sacc[4] = {};
    #pragma unroll
    for (int ks = 0; ks < 3; ks++) {
      bf16x8 ak[4];
      #pragma unroll
      for (int ni = 0; ni < 4; ni++)
        ak[ni] = *(const bf16x8*)(Kc + (ni * 16 + l15) * 192 + ks * 64 + l16 * 16);
      __builtin_amdgcn_s_setprio(1);
      #pragma unroll
      for (int ni = 0; ni < 4; ni++)
        sacc[ni] = __builtin_amdgcn_mfma_f32_16x16x32_bf16(ak[ni], qf[ks], sacc[ni], 0, 0, 0);
      __builtin_amdgcn_s_setprio(0);
    }

    // ---- per-lane softmax (q = l15 fixed; reduce across l16 groups) ----
    float a0 = fmaxf(fmaxf(sacc[0][0], sacc[0][1]), fmaxf(sacc[0][2], sacc[0][3]));
    float a1 = fmaxf(fmaxf(sacc[1][0], sacc[1][1]), fmaxf(sacc[1][2], sacc[1][3]));
    float a2 = fmaxf(fmaxf(sacc[2][0], sacc[2][1]), fmaxf(sacc[2][2], sacc[2][3]));
    float a3 = fmaxf(fmaxf(sacc[3][0], sacc[3][1]), fmaxf(sacc[3][2], sacc[3][3]));
    float v = fmaxf(fmaxf(a0, a1), fmaxf(a2, a3));
    v = fmaxf(v, __shfl_xor(v, 16));
    v = fmaxf(v, __shfl_xor(v, 32));
    // T13 defer-max: THR = 8*log2e
    if (!__all(v - mrow <= 11.54f)) {
      float mnew = fmaxf(mrow, v);
      float alpha = __builtin_amdgcn_exp2f(mrow - mnew);
      mrow = mnew;
      lrow *= alpha;
      #pragma unroll
      for (int d6 = 0; d6 < 6; d6++) {
        oacc[d6][0] *= alpha; oacc[d6][1] *= alpha;
        oacc[d6][2] *= alpha; oacc[d6][3] *= alpha;
      }
    }

    // ---- P = exp2(S^T - m), packed to bf16 in registers; accumulate l ----
    unsigned int pk[8];
    {
      float psum = 0.f;
      #pragma unroll
      for (int ni = 0; ni < 4; ni++) {
        float p0 = __builtin_amdgcn_exp2f(sacc[ni][0] - mrow);
        float p1 = __builtin_amdgcn_exp2f(sacc[ni][1] - mrow);
        float p2 = __builtin_amdgcn_exp2f(sacc[ni][2] - mrow);
        float p3 = __builtin_amdgcn_exp2f(sacc[ni][3] - mrow);
        psum += (p0 + p1) + (p2 + p3);
        pk[ni * 2]     = cvt_pk_bf16(p0, p1);
        pk[ni * 2 + 1] = cvt_pk_bf16(p2, p3);
      }
      psum += __shfl_xor(psum, 16);
      psum += __shfl_xor(psum, 32);
      lrow += psum;
    }

    // ---- O^T += V P^T : A = V sigma-fragment (b128), B = pk directly ----
    #pragma unroll
    for (int ks = 0; ks < 2; ks++) {
      bf16x8 vb[6];
      #pragma unroll
      for (int d6 = 0; d6 < 6; d6++)
        vb[d6] = *(const bf16x8*)(Vc + (d6 * 16 + l15) * 128 +
                                  (((ks * 4 + l16) ^ (l15 & 7)) << 4));
      union { unsigned int u[4]; bf16x8 v; } pf;
      pf.u[0] = pk[4 * ks];     pf.u[1] = pk[4 * ks + 1];
      pf.u[2] = pk[4 * ks + 2]; pf.u[3] = pk[4 * ks + 3];
      __builtin_amdgcn_s_setprio(1);
      #pragma unroll
      for (int d6 = 0; d6 < 6; d6++)
        oacc[d6] = __builtin_amdgcn_mfma_f32_16x16x32_bf16(vb[d6], pf.v, oacc[d6], 0, 0, 0);
      __builtin_amdgcn_s_setprio(0);
    }

    __syncthreads();  // drains prefetch vmcnt; gates buffer swap
  }

  // epilogue: normalize, write out[token][h*96+d], 8B per store
  {
    const float rl = 1.f / lrow;
    const int tok = q0 + wid * 16 + l15;
    unsigned short* Og = Oa + ((size_t)bi * SEQ + tok) * EMBED + h * HDIM;
    #pragma unroll
    for (int d6 = 0; d6 < 6; d6++) {
      uint2 o;
      o.x = cvt_pk_bf16(oacc[d6][0] * rl, oacc[d6][1] * rl);
      o.y = cvt_pk_bf16(oacc[d6][2] * rl, oacc[d6][3] * rl);
      *(uint2*)(Og + d6 * 16 + l16 * 4) = o;
    }
  }
}

extern "C" void kernel_launch(void* const* d_in, const int* in_sizes, int n_in,
                              void* d_out, int out_size, void* d_ws, size_t ws_size,
                              hipStream_t stream) {
  const float* x      = (const float*)d_in[0];
  const float* W_qkv  = (const float*)d_in[1];
  const float* b_qkv  = (const float*)d_in[2];
  const float* W_proj = (const float*)d_in[3];
  const float* b_proj = (const float*)d_in[4];
  float* out = (float*)d_out;

  char* ws = (char*)d_ws;
  size_t off = 0;
  auto alloc = [&](size_t bytes) { void* p = ws + off; off += (bytes + 255) & ~(size_t)255; return p; };
  unsigned short* xb  = (unsigned short*)alloc((size_t)NTOK * EMBED * 2);
  unsigned short* WqT = (unsigned short*)alloc((size_t)QKVN * EMBED * 2);
  unsigned short* WpT = (unsigned short*)alloc((size_t)EMBED * EMBED * 2);
  unsigned short* Qb  = (unsigned short*)alloc((size_t)NTOK * EMBED * 2);
  unsigned short* Kb  = (unsigned short*)alloc((size_t)NTOK * EMBED * 2);
  unsigned short* Vtb = (unsigned short*)alloc((size_t)NTOK * EMBED * 2);
  unsigned short* Ob  = (unsigned short*)alloc((size_t)NTOK * EMBED * 2);

  cast_x_kernel<<<dim3(NTOK * EMBED / 4 / 256), dim3(256), 0, stream>>>(
      (const float4*)x, (ushort4*)xb, NTOK * EMBED / 4);
  transpose_cast_kernel<<<dim3(QKVN / 32, EMBED / 32), dim3(256), 0, stream>>>(W_qkv, WqT, EMBED, QKVN, 1);
  transpose_cast_kernel<<<dim3(EMBED / 32, EMBED / 32), dim3(256), 0, stream>>>(W_proj, WpT, EMBED, EMBED, 0);

  // qkv: M=8192, N=2304 -> grid 64*18 = 1152 (multiple of 8)
  gemm8_kernel<0><<<dim3((NTOK / 128) * (QKVN / 128)), dim3(256), 0, stream>>>(
      xb, WqT, b_qkv, EMBED, QKVN / 128, Qb, Kb, Vtb, nullptr);

  attn_kernel<<<dim3(BATCH * NHEADS * (SEQ / 128)), dim3(512), 0, stream>>>(Qb, Kb, Vtb, Ob);

  // proj: M=8192, N=768 -> grid 64*6 = 384 (multiple of 8)
  gemm8_kernel<1><<<dim3((NTOK / 128) * (EMBED / 128)), dim3(256), 0, stream>>>(
      Ob, WpT, b_proj, EMBED, EMBED / 128, nullptr, nullptr, nullptr, out);
}

// Round 8
// 158.073 us; speedup vs baseline: 1.0070x; 1.0070x over previous
//
#include <hip/hip_runtime.h>
#include <hip/hip_bf16.h>

#define EMBED 768
#define NHEADS 8
#define HDIM 96
#define SEQ 2048
#define BATCH 4
#define NTOK (BATCH*SEQ)   // 8192
#define QKVN (3*EMBED)     // 2304

// 1/sqrt(96) * log2(e): softmax computed in exp2 domain
#define QSCALE 0.14724444f

typedef __attribute__((ext_vector_type(4))) float f32x4;
typedef __attribute__((ext_vector_type(16))) float f32x16;
typedef __attribute__((ext_vector_type(8))) __bf16 bf16x8;

__device__ __forceinline__ unsigned short f2bf(float f) {
  union { float f; unsigned int u; } c; c.f = f;
  unsigned int u = c.u;
  return (unsigned short)((u + 0x7FFFu + ((u >> 16) & 1u)) >> 16);
}

// v_cvt_pk_bf16_f32: packs (lo,hi) -> dword of 2 bf16 (gfx950)
__device__ __forceinline__ unsigned int cvt_pk_bf16(float lo, float hi) {
  unsigned int r;
  asm("v_cvt_pk_bf16_f32 %0, %1, %2" : "=v"(r) : "v"(lo), "v"(hi));
  return r;
}

__device__ __forceinline__ void gload_lds16(const void* g, void* l) {
  __builtin_amdgcn_global_load_lds(
      (const __attribute__((address_space(1))) unsigned int*)g,
      (__attribute__((address_space(3))) unsigned int*)l, 16, 0, 0);
}

// ---------------- cast x -> bf16 ----------------
__global__ __launch_bounds__(256) void cast_x_kernel(const float4* __restrict__ in,
                                                     ushort4* __restrict__ out, int n4) {
  int i = blockIdx.x * 256 + threadIdx.x;
  if (i >= n4) return;
  float4 v = in[i];
  out[i] = make_ushort4(f2bf(v.x), f2bf(v.y), f2bf(v.z), f2bf(v.w));
}

// ---------------- transpose+cast W [R][C] f32 -> [C'][R] bf16 ----------------
// remap=1 (W_qkv): out row = (c%3)*768 + c/3  (de-interleave qkv -> [which][h][d])
__global__ __launch_bounds__(256) void transpose_cast_kernel(const float* __restrict__ in,
                                                             unsigned short* __restrict__ out,
                                                             int R, int C, int remap) {
  __shared__ float t[32][33];
  int c0 = blockIdx.x * 32, r0 = blockIdx.y * 32;
  int tx = threadIdx.x & 31, ty = threadIdx.x >> 5;  // 32 x 8
  #pragma unroll
  for (int i = 0; i < 32; i += 8)
    t[ty + i][tx] = in[(size_t)(r0 + ty + i) * C + c0 + tx];
  __syncthreads();
  #pragma unroll
  for (int i = 0; i < 32; i += 8) {
    int c = c0 + ty + i;
    int rp = remap ? (c % 3) * 768 + c / 3 : c;
    out[(size_t)rp * R + r0 + tx] = f2bf(t[tx][ty + i]);
  }
}

// ---------------- GEMM, T2+T3/T4+T5 stack ----------------
template <int MODE>
__global__ __launch_bounds__(256, 2) void gemm8_kernel(
    const unsigned short* __restrict__ A, const unsigned short* __restrict__ B,
    const float* __restrict__ bias, int K, int NB,
    unsigned short* __restrict__ Qo, unsigned short* __restrict__ Ko,
    unsigned short* __restrict__ Vt, float* __restrict__ out) {
  __shared__ unsigned short As[2][128 * 64];  // 32 KB (row stride 128 B, swizzled)
  __shared__ unsigned short Bs[2][128 * 64];  // 32 KB
  const int tid = threadIdx.x;
  const int lane = tid & 63, wid = tid >> 6;
  const int wr = wid >> 1, wc = wid & 1;
  const int l15 = lane & 15, l16 = lane >> 4;
  const int cpx = gridDim.x >> 3;
  const int bid = blockIdx.x;
  const int swz = (bid & 7) * cpx + (bid >> 3);
  const int my = swz / NB, nx = swz - my * NB;
  const int m0 = my * 128, n0 = nx * 128;

  auto stage_half = [&](int buf, int kt, int half) {
    const unsigned short* src = half ? B : A;
    const int base0 = half ? n0 : m0;
    char* dst = (char*)(half ? &Bs[buf][0] : &As[buf][0]);
    #pragma unroll
    for (int i = 0; i < 4; i++) {
      int c = i * 256 + tid;
      int r = c >> 3, s = c & 7;
      gload_lds16(src + (size_t)(base0 + r) * K + kt * 64 + ((s ^ (r & 7)) << 3),
                  dst + (i * 256 + wid * 64) * 16);
    }
  };

  f32x4 acc[4][4] = {};
  const int xr = (l15 & 7) << 4;

  stage_half(0, 0, 0);
  stage_half(0, 0, 1);
  asm volatile("s_waitcnt vmcnt(0)" ::: "memory");
  __builtin_amdgcn_s_barrier();

  const int NT = K >> 6;
  for (int t = 0; t < NT; ++t) {
    const int cur = t & 1;
    const char* Ac = (const char*)&As[cur][0];
    const char* Bc = (const char*)&Bs[cur][0];
    #pragma unroll
    for (int kh = 0; kh < 2; ++kh) {
      bf16x8 af[4], bfr[4];
      #pragma unroll
      for (int mi = 0; mi < 4; mi++)
        af[mi] = *(const bf16x8*)(Ac + (wr * 64 + mi * 16 + l15) * 128 +
                                  ((kh * 64 + l16 * 16) ^ xr));
      #pragma unroll
      for (int ni = 0; ni < 4; ni++)
        bfr[ni] = *(const bf16x8*)(Bc + (wc * 64 + ni * 16 + l15) * 128 +
                                   ((kh * 64 + l16 * 16) ^ xr));
      if (t + 1 < NT) stage_half(cur ^ 1, t + 1, kh);
      __builtin_amdgcn_s_barrier();
      __builtin_amdgcn_s_setprio(1);
      #pragma unroll
      for (int mi = 0; mi < 4; mi++)
        #pragma unroll
        for (int ni = 0; ni < 4; ni++)
          acc[mi][ni] = __builtin_amdgcn_mfma_f32_16x16x32_bf16(af[mi], bfr[ni], acc[mi][ni], 0, 0, 0);
      __builtin_amdgcn_s_setprio(0);
      __builtin_amdgcn_s_barrier();
    }
    asm volatile("s_waitcnt lgkmcnt(0)" ::: "memory");
    asm volatile("s_waitcnt vmcnt(0)" ::: "memory");
    __builtin_amdgcn_sched_barrier(0);
    __builtin_amdgcn_s_barrier();
  }

  if (MODE == 0) {
    #pragma unroll
    for (int mi = 0; mi < 4; mi++) {
      #pragma unroll
      for (int ni = 0; ni < 4; ni++) {
        int base = n0 + wc * 64 + ni * 16;
        int which = base / 768;
        int hd = base - which * 768;
        int h = hd / 96;
        int d0 = hd - h * 96;
        float bb = bias[(hd + l15) * 3 + which];
        int rowb = m0 + wr * 64 + mi * 16 + l16 * 4;
        int bi = rowb >> 11, nnb = rowb & 2047;
        size_t bh = (size_t)(bi * NHEADS + h);
        if (which == 2) {
          // phi: swap bits 2<->3 within each 16-block (involution) so the
          // attn 32x32 S^T C-layout feeds PV's B-operand directly
          int nn2 = (nnb & ~12) | ((nnb & 4) << 1) | ((nnb & 8) >> 1);
          float v0 = acc[mi][ni][0] + bb, v1 = acc[mi][ni][1] + bb;
          float v2 = acc[mi][ni][2] + bb, v3 = acc[mi][ni][3] + bb;
          uint2 pk;
          pk.x = cvt_pk_bf16(v0, v1);
          pk.y = cvt_pk_bf16(v2, v3);
          *(uint2*)(Vt + (bh * HDIM + d0 + l15) * SEQ + nn2) = pk;
        } else {
          #pragma unroll
          for (int j = 0; j < 4; j++) {
            float v = acc[mi][ni][j] + bb;
            int nn = nnb + j;
            if (which == 0) Qo[(bh * SEQ + nn) * HDIM + d0 + l15] = f2bf(v * QSCALE);
            else            Ko[(bh * SEQ + nn) * HDIM + d0 + l15] = f2bf(v);
          }
        }
      }
    }
  } else {
    #pragma unroll
    for (int mi = 0; mi < 4; mi++) {
      #pragma unroll
      for (int ni = 0; ni < 4; ni++) {
        int col = n0 + wc * 64 + ni * 16 + l15;
        float bb = bias[col];
        #pragma unroll
        for (int j = 0; j < 4; j++) {
          int row = m0 + wr * 64 + mi * 16 + l16 * 4 + j;
          out[(size_t)row * EMBED + col] = acc[mi][ni][j] + bb;
        }
      }
    }
  }
}

// ---------------- flash attention v4: 4 waves x 32 q, 32x32x16 MFMA, register P ----
// Q [B*H][N][96] bf16 (pre-scaled), K same, Vt [B*H][96][N] bf16 (phi-permuted cols).
// KVBLK=64 double-buffered, 1 barrier/iter. LDS 48 KB.
// K LDS layout: [k-octet o=0..11][kv 0..63] 16B granules -> conflict-free A-frag reads.
__global__ __launch_bounds__(256) void attn_kernel(
    const unsigned short* __restrict__ Q, const unsigned short* __restrict__ Kd,
    const unsigned short* __restrict__ Vt, unsigned short* __restrict__ Oa) {
  __shared__ unsigned short Ks[2][64 * 96];   // [o][kv] granules, 12 KB per buf
  __shared__ unsigned short Vs[2][96 * 64];   // [d][slot^(d&7)] granules, 12 KB

  const int tid = threadIdx.x, lane = tid & 63, wid = tid >> 6;  // 4 waves
  const int l31 = lane & 31, hi = lane >> 5;
  const int bid = blockIdx.x;
  const int swz = (bid & 7) * 64 + (bid >> 3);
  const int qb_ = swz & 15, bh = swz >> 4;
  const int bi = bh >> 3, h = bh & 7;
  const int q0 = qb_ * 128;

  const unsigned short* Qg = Q + ((size_t)bh * SEQ + q0) * HDIM;
  const unsigned short* Kg = Kd + (size_t)bh * SEQ * HDIM;
  const unsigned short* Vg = Vt + (size_t)bh * HDIM * SEQ;

  // Q B-frags: q = wid*32 + l31 (n = lane&31), k = ks*16 + hi*8 + j
  bf16x8 qf[6];
  #pragma unroll
  for (int ks = 0; ks < 6; ks++)
    qf[ks] = *(const bf16x8*)(Qg + (size_t)(wid * 32 + l31) * HDIM + ks * 16 + hi * 8);

  auto stageKV = [&](int buf, int k0) {
    // K: lds granule g = o*64 + kv  <-  global K[k0+kv][o*8 .. +7]
    #pragma unroll
    for (int i = 0; i < 3; i++) {
      int g = i * 256 + tid;
      int o = g >> 6, kv = g & 63;
      gload_lds16(Kg + (size_t)(k0 + kv) * HDIM + o * 8,
                  (char*)&Ks[buf][0] + (i * 256 + wid * 64) * 16);
    }
    // V: [d][slot s ^ (d&7)] via pre-swizzled global source
    #pragma unroll
    for (int i = 0; i < 3; i++) {
      int idx = i * 256 + tid;
      int d = idx >> 3, s = idx & 7;
      gload_lds16(Vg + (size_t)d * SEQ + k0 + ((s ^ (d & 7)) << 3),
                  (char*)&Vs[buf][0] + (i * 256 + wid * 64) * 16);
    }
  };

  f32x16 oacc[3] = {};   // O^T: col q=l31, row d = db*32 + (r&3)+8*(r>>2)+4*hi
  float mrow = -__builtin_inff(), lrow = 0.f;

  stageKV(0, 0);
  __syncthreads();

  for (int kb = 0; kb < SEQ / 64; kb++) {
    const int cur = kb & 1;
    if (kb + 1 < SEQ / 64) stageKV(cur ^ 1, (kb + 1) * 64);

    const char* Kc = (const char*)&Ks[cur][0];
    const char* Vc = (const char*)&Vs[cur][0];

    // ---- S^T = K Q^T : sacc[kbk], lane holds kv = kbk*32+(r&3)+8*(r>>2)+4hi, q = l31
    f32x16 sacc[2] = {};
    #pragma unroll
    for (int ks = 0; ks < 6; ks++) {
      bf16x8 ak0 = *(const bf16x8*)(Kc + (((2 * ks + hi) * 64) + l31) * 16);
      bf16x8 ak1 = *(const bf16x8*)(Kc + (((2 * ks + hi) * 64) + 32 + l31) * 16);
      __builtin_amdgcn_s_setprio(1);
      sacc[0] = __builtin_amdgcn_mfma_f32_32x32x16_bf16(ak0, qf[ks], sacc[0], 0, 0, 0);
      sacc[1] = __builtin_amdgcn_mfma_f32_32x32x16_bf16(ak1, qf[ks], sacc[1], 0, 0, 0);
      __builtin_amdgcn_s_setprio(0);
    }

    // ---- per-lane softmax: one q per lane, 32 kv values in-register ----
    float v = fmaxf(sacc[0][0], sacc[1][0]);
    #pragma unroll
    for (int r = 1; r < 16; r++)
      v = fmaxf(v, fmaxf(sacc[0][r], sacc[1][r]));
    v = fmaxf(v, __shfl_xor(v, 32));
    // T13 defer-max: THR = 8*log2e
    if (!__all(v - mrow <= 11.54f)) {
      float mnew = fmaxf(mrow, v);
      float alpha = __builtin_amdgcn_exp2f(mrow - mnew);
      mrow = mnew;
      lrow *= alpha;
      #pragma unroll
      for (int db = 0; db < 3; db++)
        #pragma unroll
        for (int r = 0; r < 16; r++)
          oacc[db][r] *= alpha;
    }

    // ---- P = exp2(S^T - m) packed to bf16 in registers; accumulate l ----
    unsigned int pk[2][8];
    float psum = 0.f;
    #pragma unroll
    for (int kbk = 0; kbk < 2; kbk++)
      #pragma unroll
      for (int j2 = 0; j2 < 8; j2++) {
        float p0 = __builtin_amdgcn_exp2f(sacc[kbk][2 * j2] - mrow);
        float p1 = __builtin_amdgcn_exp2f(sacc[kbk][2 * j2 + 1] - mrow);
        psum += p0 + p1;
        pk[kbk][j2] = cvt_pk_bf16(p0, p1);
      }
    psum += __shfl_xor(psum, 32);
    lrow += psum;

    // ---- O^T += V P^T : A = V phi-fragment (b128), B = pk directly ----
    #pragma unroll
    for (int kbk = 0; kbk < 2; kbk++)
      #pragma unroll
      for (int t = 0; t < 2; t++) {
        union { unsigned int u[4]; bf16x8 v; } pf;
        pf.u[0] = pk[kbk][4 * t];     pf.u[1] = pk[kbk][4 * t + 1];
        pf.u[2] = pk[kbk][4 * t + 2]; pf.u[3] = pk[kbk][4 * t + 3];
        const int sidx = (kbk * 2 + t) * 2 + hi;  // 16B-slot in V row
        __builtin_amdgcn_s_setprio(1);
        #pragma unroll
        for (int db = 0; db < 3; db++) {
          int d = db * 32 + l31;
          bf16x8 vb = *(const bf16x8*)(Vc + d * 128 + ((sidx ^ (d & 7)) << 4));
          oacc[db] = __builtin_amdgcn_mfma_f32_32x32x16_bf16(vb, pf.v, oacc[db], 0, 0, 0);
        }
        __builtin_amdgcn_s_setprio(0);
      }

    __syncthreads();  // drains prefetch vmcnt; gates buffer swap
  }

  // epilogue: normalize, write out[token][h*96+d], 8B per store
  {
    const float rl = 1.f / lrow;
    const int tok = q0 + wid * 32 + l31;
    unsigned short* Og = Oa + ((size_t)bi * SEQ + tok) * EMBED + h * HDIM;
    #pragma unroll
    for (int db = 0; db < 3; db++)
      #pragma unroll
      for (int rq = 0; rq < 4; rq++) {
        uint2 o;
        o.x = cvt_pk_bf16(oacc[db][4 * rq] * rl, oacc[db][4 * rq + 1] * rl);
        o.y = cvt_pk_bf16(oacc[db][4 * rq + 2] * rl, oacc[db][4 * rq + 3] * rl);
        *(uint2*)(Og + db * 32 + rq * 8 + hi * 4) = o;
      }
  }
}

extern "C" void kernel_launch(void* const* d_in, const int* in_sizes, int n_in,
                              void* d_out, int out_size, void* d_ws, size_t ws_size,
                              hipStream_t stream) {
  const float* x      = (const float*)d_in[0];
  const float* W_qkv  = (const float*)d_in[1];
  const float* b_qkv  = (const float*)d_in[2];
  const float* W_proj = (const float*)d_in[3];
  const float* b_proj = (const float*)d_in[4];
  float* out = (float*)d_out;

  char* ws = (char*)d_ws;
  size_t off = 0;
  auto alloc = [&](size_t bytes) { void* p = ws + off; off += (bytes + 255) & ~(size_t)255; return p; };
  unsigned short* xb  = (unsigned short*)alloc((size_t)NTOK * EMBED * 2);
  unsigned short* WqT = (unsigned short*)alloc((size_t)QKVN * EMBED * 2);
  unsigned short* WpT = (unsigned short*)alloc((size_t)EMBED * EMBED * 2);
  unsigned short* Qb  = (unsigned short*)alloc((size_t)NTOK * EMBED * 2);
  unsigned short* Kb  = (unsigned short*)alloc((size_t)NTOK * EMBED * 2);
  unsigned short* Vtb = (unsigned short*)alloc((size_t)NTOK * EMBED * 2);
  unsigned short* Ob  = (unsigned short*)alloc((size_t)NTOK * EMBED * 2);

  cast_x_kernel<<<dim3(NTOK * EMBED / 4 / 256), dim3(256), 0, stream>>>(
      (const float4*)x, (ushort4*)xb, NTOK * EMBED / 4);
  transpose_cast_kernel<<<dim3(QKVN / 32, EMBED / 32), dim3(256), 0, stream>>>(W_qkv, WqT, EMBED, QKVN, 1);
  transpose_cast_kernel<<<dim3(EMBED / 32, EMBED / 32), dim3(256), 0, stream>>>(W_proj, WpT, EMBED, EMBED, 0);

  // qkv: M=8192, N=2304 -> grid 64*18 = 1152 (multiple of 8)
  gemm8_kernel<0><<<dim3((NTOK / 128) * (QKVN / 128)), dim3(256), 0, stream>>>(
      xb, WqT, b_qkv, EMBED, QKVN / 128, Qb, Kb, Vtb, nullptr);

  attn_kernel<<<dim3(BATCH * NHEADS * (SEQ / 128)), dim3(256), 0, stream>>>(Qb, Kb, Vtb, Ob);

  // proj: M=8192, N=768 -> grid 64*6 = 384 (multiple of 8)
  gemm8_kernel<1><<<dim3((NTOK / 128) * (EMBED / 128)), dim3(256), 0, stream>>>(
      Ob, WpT, b_proj, EMBED, EMBED / 128, nullptr, nullptr, nullptr, out);
}